// Round 11
// baseline (273.554 us; speedup 1.0000x reference)
//
#include <hip/hip_runtime.h>
#include <hip/hip_bf16.h>

#define NF 256
#define NH 128
#define PSZ_SH 7            // 128 nodes per bucket
#define MAXP 1024           // max buckets (N <= 131072)
#define NCB 512             // chunk blocks for count/scatter

typedef __attribute__((ext_vector_type(8))) short short8;
typedef __attribute__((ext_vector_type(4))) float float4v;

static __device__ __forceinline__ ushort f2bf(float f) {
  unsigned u = __float_as_uint(f);
  u = (u + 0x7fffu + ((u >> 16) & 1u)) >> 16;   // round-to-nearest-even
  return (ushort)u;
}
static __device__ __forceinline__ float bflo(unsigned u) { return __uint_as_float(u << 16); }
static __device__ __forceinline__ float bfhi(unsigned u) { return __uint_as_float(u & 0xffff0000u); }

static __device__ __forceinline__ short8 pack_bf8(float4 v0, float4 v1) {
  short8 r;
  r[0] = (short)f2bf(v0.x); r[1] = (short)f2bf(v0.y);
  r[2] = (short)f2bf(v0.z); r[3] = (short)f2bf(v0.w);
  r[4] = (short)f2bf(v1.x); r[5] = (short)f2bf(v1.y);
  r[6] = (short)f2bf(v1.z); r[7] = (short)f2bf(v1.w);
  return r;
}

// ------- initall: W1 frags [0,128) | Wc [128] | per-chunk bucket histograms [129, 129+NCB) -------
__global__ __launch_bounds__(256) void k_initall(
    const int* __restrict__ ei, int E, int P, int* __restrict__ bcnt, int chunk,
    const float* __restrict__ W1, ushort* __restrict__ Wfr,
    const float* __restrict__ W2, const float* __restrict__ Wfv,
    const float* __restrict__ b2, const float* __restrict__ bfv,
    float* __restrict__ Wc) {
  int b = blockIdx.x;
  if (b < 128) {
    int g = b * 256 + threadIdx.x;
    int ii   = g & 7;
    int lane = (g >> 3) & 63;
    int t    = (g >> 9) & 7;
    int ks   = g >> 12;
    int k = ks * 32 + ((lane >> 4) << 3) + ii;
    int c = t * 16 + (lane & 15);
    Wfr[g] = f2bf(W1[(size_t)k * NH + c]);
  } else if (b == 128) {
    __shared__ float wl[NH];
    if (threadIdx.x < NH) wl[threadIdx.x] = Wfv[threadIdx.x];
    __syncthreads();
    if (threadIdx.x < NH) {
      int i = threadIdx.x;
      const float4* w4 = reinterpret_cast<const float4*>(&W2[(size_t)i * NH]);
      float s = 0.f;
#pragma unroll 8
      for (int k = 0; k < NH / 4; ++k) {
        float4 v = w4[k];
        s += v.x * wl[4 * k] + v.y * wl[4 * k + 1] + v.z * wl[4 * k + 2] + v.w * wl[4 * k + 3];
      }
      Wc[i] = s;
      if (i == 0) {
        float c = 0.f;
        for (int k = 0; k < NH; ++k) c += b2[k] * wl[k];
        Wc[NH] = c + bfv[0];
      }
    }
  } else {
    int cb = b - 129;
    __shared__ int hc[MAXP];
    for (int j = threadIdx.x; j < P; j += 256) hc[j] = 0;
    __syncthreads();
    int start = cb * chunk;
    int endE = min(start + chunk, E);
    for (int e = start + (int)threadIdx.x; e < endE; e += 256)
      atomicAdd(&hc[ei[E + e] >> PSZ_SH], 1);
    __syncthreads();
    for (int j = threadIdx.x; j < P; j += 256) bcnt[cb * P + j] = hc[j];
  }
}

// ---------------- scanA: per-bucket exclusive prefix over chunks; ptot ----------------
__global__ __launch_bounds__(NCB) void k_scanA(const int* __restrict__ bcnt,
                                               int* __restrict__ bloc,
                                               int* __restrict__ ptot, int P) {
  __shared__ int ws[NCB / 64];
  int p = blockIdx.x, tid = threadIdx.x, lane = tid & 63, wid = tid >> 6;
  int v = bcnt[tid * P + p];
  int pre = v;
#pragma unroll
  for (int m = 1; m < 64; m <<= 1) {
    int t = __shfl_up(pre, m, 64);
    if (lane >= m) pre += t;
  }
  if (lane == 63) ws[wid] = pre;
  __syncthreads();
  if (tid == 0) {
    int run = 0;
#pragma unroll
    for (int j = 0; j < NCB / 64; ++j) { int t = ws[j]; ws[j] = run; run += t; }
    ptot[p] = run;
  }
  __syncthreads();
  bloc[tid * P + p] = ws[wid] + pre - v;
}

// ---------------- scanB: exclusive scan of ptot -> pbase ----------------
__global__ __launch_bounds__(1024) void k_scanB(const int* __restrict__ ptot,
                                                int* __restrict__ pbase, int P, int E) {
  __shared__ int ws[16];
  int tid = threadIdx.x, lane = tid & 63, wid = tid >> 6;
  int v = (tid < P) ? ptot[tid] : 0;
  int pre = v;
#pragma unroll
  for (int m = 1; m < 64; m <<= 1) {
    int t = __shfl_up(pre, m, 64);
    if (lane >= m) pre += t;
  }
  if (lane == 63) ws[wid] = pre;
  __syncthreads();
  if (tid == 0) {
    int run = 0;
#pragma unroll
    for (int j = 0; j < 16; ++j) { int t = ws[j]; ws[j] = run; run += t; }
  }
  __syncthreads();
  if (tid < P) pbase[tid] = ws[wid] + pre - v;
  if (tid == 0) pbase[P] = E;
}

// ---------------- scatter: edges -> bucket-contiguous packed sub (LDS cursors) ----------------
__global__ __launch_bounds__(256) void k_scatter(const int* __restrict__ ei, int E,
                                                 const int* __restrict__ pbase,
                                                 const int* __restrict__ bloc,
                                                 uint* __restrict__ sub, int chunk, int P) {
  __shared__ int cur[MAXP];
  int b = blockIdx.x;
  for (int j = threadIdx.x; j < P; j += 256) cur[j] = pbase[j] + bloc[b * P + j];
  __syncthreads();
  int start = b * chunk;
  int endE = min(start + chunk, E);
  for (int e = start + (int)threadIdx.x; e < endE; e += 256) {
    int s = ei[e];
    int d = ei[E + e];
    int pos = atomicAdd(&cur[d >> PSZ_SH], 1);
    sub[pos] = (uint)s | ((uint)(d & ((1 << PSZ_SH) - 1)) << 20);
  }
}

// ---------------- bucket: per-bucket hist -> rowptr/deg/dinv + csr fill (LDS only) ----------------
__global__ __launch_bounds__(256) void k_bucket(const uint* __restrict__ sub,
                                                const int* __restrict__ pbase,
                                                int* __restrict__ rowptr, int* __restrict__ deg,
                                                float* __restrict__ dinv, int* __restrict__ csr,
                                                int N) {
  __shared__ int hist[1 << PSZ_SH];
  __shared__ int curL[1 << PSZ_SH];
  __shared__ int wsum[2];
  const int p = blockIdx.x, tid = threadIdx.x;
  const int base = pbase[p];
  const int cnt = pbase[p + 1] - base;
  const int node0 = p << PSZ_SH;
  if (tid < (1 << PSZ_SH)) hist[tid] = 0;
  __syncthreads();
  for (int e = tid; e < cnt; e += 256) atomicAdd(&hist[sub[base + e] >> 20], 1);
  __syncthreads();
  int d = 0, pre = 0;
  if (tid < (1 << PSZ_SH)) {
    d = hist[tid];
    pre = d;
#pragma unroll
    for (int m = 1; m < 64; m <<= 1) {
      int t = __shfl_up(pre, m, 64);
      if ((tid & 63) >= m) pre += t;
    }
    if ((tid & 63) == 63) wsum[tid >> 6] = pre;
  }
  __syncthreads();
  if (tid < (1 << PSZ_SH)) {
    int excl = base + ((tid >= 64) ? wsum[0] : 0) + pre - d;
    curL[tid] = excl;
    int node = node0 + tid;
    if (node < N) {
      rowptr[node] = excl;
      deg[node] = d;
      dinv[node] = rsqrtf((float)d + 1.0f);
    }
  }
  __syncthreads();
  for (int e = tid; e < cnt; e += 256) {
    uint v = sub[base + e];
    int pos = atomicAdd(&curL[v >> 20], 1);
    csr[pos] = (int)(v & 0xFFFFFu);
  }
}

// ---------------- GEMM1 v3 (MFMA): hs = dinv*(x@W1), bf16, QUARTER-MAJOR output ----------------
// hq layout: quarter q (32 feats) at hs + q*N*16 uints; node row = 16 uints (64B)
__global__ __launch_bounds__(256, 2) void k_gemm1(
    const float* __restrict__ x, const ushort* __restrict__ Wf,
    const float* __restrict__ dinv, uint* __restrict__ hs, int N) {
  __shared__ ushort Ol[64][136];
  const int tid = threadIdx.x;
  const int w = tid >> 6, l = tid & 63;
  const int row0 = blockIdx.x * 64;
  const int arow = row0 + 16 * w + (l & 15);
  const int kg = l >> 4;
  const bool rv = arow < N;
  const float* xr = &x[(size_t)(rv ? arow : 0) * NF + kg * 8];

  float4 xf0[8], xf1[8];
#pragma unroll
  for (int ks = 0; ks < 8; ++ks) {
    xf0[ks] = *reinterpret_cast<const float4*>(&xr[ks * 32]);
    xf1[ks] = *reinterpret_cast<const float4*>(&xr[ks * 32 + 4]);
  }
  __builtin_amdgcn_sched_barrier(0);

  short8 afr[8];
#pragma unroll
  for (int ks = 0; ks < 8; ++ks) {
    float4 v0 = xf0[ks], v1 = xf1[ks];
    if (!rv) { v0 = make_float4(0.f, 0.f, 0.f, 0.f); v1 = v0; }
    afr[ks] = pack_bf8(v0, v1);
  }

  const short8* Wb = reinterpret_cast<const short8*>(Wf);
  float4v acc[8];
#pragma unroll
  for (int t = 0; t < 8; ++t) acc[t] = (float4v){0.f, 0.f, 0.f, 0.f};
  short8 bc[8], bn[8];
#pragma unroll
  for (int ks = 0; ks < 8; ++ks) bc[ks] = Wb[(ks * 8 + 0) * 64 + l];
#pragma unroll
  for (int tp = 0; tp < 4; ++tp) {
    const int t0 = 2 * tp, t1 = 2 * tp + 1;
#pragma unroll
    for (int ks = 0; ks < 8; ++ks) bn[ks] = Wb[(ks * 8 + t1) * 64 + l];
    __builtin_amdgcn_sched_barrier(0);
#pragma unroll
    for (int ks = 0; ks < 8; ++ks)
      acc[t0] = __builtin_amdgcn_mfma_f32_16x16x32_bf16(afr[ks], bc[ks], acc[t0], 0, 0, 0);
    if (tp < 3) {
#pragma unroll
      for (int ks = 0; ks < 8; ++ks) bc[ks] = Wb[(ks * 8 + t1 + 1) * 64 + l];
      __builtin_amdgcn_sched_barrier(0);
    }
#pragma unroll
    for (int ks = 0; ks < 8; ++ks)
      acc[t1] = __builtin_amdgcn_mfma_f32_16x16x32_bf16(afr[ks], bn[ks], acc[t1], 0, 0, 0);
  }

  float dj[4];
#pragma unroll
  for (int j = 0; j < 4; ++j) {
    int grow = row0 + 16 * w + (l >> 4) * 4 + j;
    dj[j] = (grow < N) ? dinv[grow] : 0.f;
  }
#pragma unroll
  for (int t = 0; t < 8; ++t)
#pragma unroll
    for (int j = 0; j < 4; ++j)
      Ol[16 * w + (l >> 4) * 4 + j][16 * t + (l & 15)] = f2bf(acc[t][j] * dj[j]);
  __syncthreads();
  {
    const int r = tid >> 2, grow = row0 + r;
    const int qt = tid & 3;
    if (grow < N) {
      uint* dstq = hs + (size_t)qt * N * 16 + (size_t)grow * 16;
#pragma unroll
      for (int q2 = 0; q2 < 4; ++q2) {
        uint4 v = *reinterpret_cast<const uint4*>(&Ol[r][qt * 32 + q2 * 8]);
        *reinterpret_cast<uint4*>(&dstq[q2 * 4]) = v;
      }
    }
  }
}

// ---------------- agg pass (one feature quarter): z_partial = relu-dot over 32 feats ----------------
// hq: this quarter's slice (node row = 16 uints = 64B, L2-resident 6.4MB)
__global__ __launch_bounds__(256) void k_aggq(
    const uint* __restrict__ hq, const int* __restrict__ rowptr,
    const int* __restrict__ deg, const int* __restrict__ csr,
    const float* __restrict__ dinv, const float* __restrict__ b1q,
    const float* __restrict__ Wcq, float* __restrict__ zp, int N) {
  int g = blockIdx.x * blockDim.x + threadIdx.x;
  int i = g >> 6;
  if (i >= N) return;
  int lane = threadIdx.x & 63;
  int q = lane >> 4;        // edge slot 0..3
  int sub = lane & 15;      // uint within 64B row (feats 2sub, 2sub+1)

  float ax, ay;
  {  // self-loop: quarter-slot 0 only (exact unpack)
    uint u = hq[(size_t)i * 16 + sub];
    if (q) u = 0u;
    ax = bflo(u); ay = bfhi(u);
  }

  int kk = rowptr[i];
  const int end = kk + deg[i];
  for (; kk + 15 < end; kk += 16) {   // 16 edges/iter, 4 per slot (4 loads in flight)
    int c0 = csr[kk + q];
    int c1 = csr[kk + 4 + q];
    int c2 = csr[kk + 8 + q];
    int c3 = csr[kk + 12 + q];
    uint u0 = hq[(size_t)c0 * 16 + sub];
    uint u1 = hq[(size_t)c1 * 16 + sub];
    uint u2 = hq[(size_t)c2 * 16 + sub];
    uint u3 = hq[(size_t)c3 * 16 + sub];
    ax += bflo(u0); ay += __uint_as_float(u0);   // hi: garbage-mantissa trick
    ax += bflo(u1); ay += __uint_as_float(u1);
    ax += bflo(u2); ay += __uint_as_float(u2);
    ax += bflo(u3); ay += __uint_as_float(u3);
  }
  for (; kk + 3 < end; kk += 4) {
    int c = csr[kk + q];
    uint u = hq[(size_t)c * 16 + sub];
    ax += bflo(u); ay += __uint_as_float(u);
  }
  int r = end - kk;
  if (r > 0) {
    int c = csr[kk + (q < r ? q : r - 1)];
    uint u = hq[(size_t)c * 16 + sub];
    if (q >= r) u = 0u;
    ax += bflo(u); ay += __uint_as_float(u);
  }

  // combine the 4 edge slots
  ax += __shfl_xor(ax, 16, 64); ax += __shfl_xor(ax, 32, 64);
  ay += __shfl_xor(ay, 16, 64); ay += __shfl_xor(ay, 32, 64);

  float d = dinv[i];
  float2 bb = reinterpret_cast<const float2*>(b1q)[sub];
  float2 ww = reinterpret_cast<const float2*>(Wcq)[sub];
  float s = fmaxf(fmaf(d, ax, bb.x), 0.f) * ww.x
          + fmaxf(fmaf(d, ay, bb.y), 0.f) * ww.y;
#pragma unroll
  for (int m = 8; m >= 1; m >>= 1) s += __shfl_xor(s, m, 64);
  if (lane == 0) zp[i] = s;
}

// ---------------- z combine: z = sum of 4 partials; zs, out init ----------------
__global__ void k_zcomb(const float* __restrict__ zp, const float* __restrict__ dinv,
                        const float* __restrict__ Wc, float* __restrict__ zs,
                        float* __restrict__ out, int N) {
  int i = blockIdx.x * blockDim.x + threadIdx.x;
  if (i >= N) return;
  float z = (zp[i] + zp[(size_t)N + i]) + (zp[(size_t)2 * N + i] + zp[(size_t)3 * N + i]);
  float d = dinv[i];
  float zsv = d * z;
  zs[i] = zsv;
  out[i] = d * zsv + Wc[NH];
}

// ---------------- layer2 gather: out[i] += dinv[i] * sum zs[src] ----------------
__global__ void k_out2(const int* __restrict__ rowptr, const int* __restrict__ deg,
                       const int* __restrict__ csr, const float* __restrict__ zs,
                       const float* __restrict__ dinv, float* __restrict__ out, int N) {
  int i = blockIdx.x * blockDim.x + threadIdx.x;
  if (i >= N) return;
  int k = rowptr[i], end = k + deg[i];
  float s = 0.f;
  for (; k + 3 < end; k += 4) {
    float t0 = zs[csr[k]], t1 = zs[csr[k + 1]], t2 = zs[csr[k + 2]], t3 = zs[csr[k + 3]];
    s += (t0 + t1) + (t2 + t3);
  }
  for (; k < end; ++k) s += zs[csr[k]];
  out[i] += dinv[i] * s;
}

extern "C" void kernel_launch(void* const* d_in, const int* in_sizes, int n_in,
                              void* d_out, int out_size, void* d_ws, size_t ws_size,
                              hipStream_t stream) {
  const float* x  = (const float*)d_in[0];
  const int*   ei = (const int*)d_in[1];
  const float* W1 = (const float*)d_in[2];
  const float* b1 = (const float*)d_in[3];
  const float* W2 = (const float*)d_in[4];
  const float* b2 = (const float*)d_in[5];
  const float* Wf = (const float*)d_in[6];
  const float* bf = (const float*)d_in[7];
  const int N = in_sizes[0] / NF;
  const int E = in_sizes[1] / 2;
  const int P = (N + (1 << PSZ_SH) - 1) >> PSZ_SH;   // 782 buckets
  const int chunk = (E + NCB - 1) / NCB;

  char* ws = (char*)d_ws;
  size_t off = 0;
  auto alloc = [&](size_t bytes) {
    void* p = ws + off;
    off = (off + bytes + 255) & ~(size_t)255;
    return p;
  };
  uint*   hs     = (uint*)alloc((size_t)N * NH * 2);      // 25.6 MB, quarter-major
  ushort* Wfrag  = (ushort*)alloc((size_t)NF * NH * 2);   // 64 KB
  int*    csr    = (int*)alloc((size_t)E * 4);            // 6.4 MB
  uint*   sub    = (uint*)alloc((size_t)E * 4);           // 6.4 MB
  int*    deg    = (int*)alloc((size_t)N * 4);
  int*    rowptr = (int*)alloc((size_t)N * 4);
  float*  dinv   = (float*)alloc((size_t)N * 4);
  float*  zs     = (float*)alloc((size_t)N * 4);
  float*  zp     = (float*)alloc((size_t)N * 4 * 4);      // 1.6 MB (4 partials)
  float*  Wc     = (float*)alloc(132 * 4);
  int*    bcnt   = (int*)alloc((size_t)NCB * P * 4);      // 1.6 MB
  int*    bloc   = (int*)alloc((size_t)NCB * P * 4);      // 1.6 MB
  int*    ptot   = (int*)alloc((size_t)P * 4);
  int*    pbase  = (int*)alloc((size_t)(P + 1) * 4);
  float*  out    = (float*)d_out;

  const int b = 256;
  k_initall<<<129 + NCB, b, 0, stream>>>(ei, E, P, bcnt, chunk,
                                         W1, Wfrag, W2, Wf, b2, bf, Wc);
  k_scanA  <<<P, NCB, 0, stream>>>(bcnt, bloc, ptot, P);
  k_scanB  <<<1, 1024, 0, stream>>>(ptot, pbase, P, E);
  k_scatter<<<NCB, b, 0, stream>>>(ei, E, pbase, bloc, sub, chunk, P);
  k_bucket <<<P, b, 0, stream>>>(sub, pbase, rowptr, deg, dinv, csr, N);
  k_gemm1  <<<(N + 63) / 64, 256, 0, stream>>>(x, Wfrag, dinv, hs, N);
  const int aggGrid = (int)(((size_t)N * 64 + b - 1) / b);
  for (int p4 = 0; p4 < 4; ++p4) {
    k_aggq <<<aggGrid, b, 0, stream>>>(hs + (size_t)p4 * N * 16, rowptr, deg, csr,
                                       dinv, b1 + p4 * 32, Wc + p4 * 32,
                                       zp + (size_t)p4 * N, N);
  }
  k_zcomb  <<<(N + b - 1) / b, b, 0, stream>>>(zp, dinv, Wc, zs, out, N);
  k_out2   <<<(N + b - 1) / b, b, 0, stream>>>(rowptr, deg, csr, zs, dinv, out, N);
}

// Round 12
// 157.389 us; speedup vs baseline: 1.7381x; 1.7381x over previous
//
#include <hip/hip_runtime.h>
#include <hip/hip_bf16.h>

#define NF 256
#define NH 128
#define PSZ_SH 7            // 128 nodes per bucket
#define MAXP 1024           // max buckets (N <= 131072)
#define NCB 512             // chunk blocks for count/scatter

typedef __attribute__((ext_vector_type(8))) short short8;
typedef __attribute__((ext_vector_type(4))) float float4v;

static __device__ __forceinline__ ushort f2bf(float f) {
  unsigned u = __float_as_uint(f);
  u = (u + 0x7fffu + ((u >> 16) & 1u)) >> 16;   // round-to-nearest-even
  return (ushort)u;
}
static __device__ __forceinline__ float bflo(unsigned u) { return __uint_as_float(u << 16); }
static __device__ __forceinline__ float bfhi(unsigned u) { return __uint_as_float(u & 0xffff0000u); }

static __device__ __forceinline__ short8 pack_bf8(float4 v0, float4 v1) {
  short8 r;
  r[0] = (short)f2bf(v0.x); r[1] = (short)f2bf(v0.y);
  r[2] = (short)f2bf(v0.z); r[3] = (short)f2bf(v0.w);
  r[4] = (short)f2bf(v1.x); r[5] = (short)f2bf(v1.y);
  r[6] = (short)f2bf(v1.z); r[7] = (short)f2bf(v1.w);
  return r;
}

// ------- initall: W1 frags [0,128) | Wc [128] | per-chunk bucket histograms [129, 129+NCB) -------
__global__ __launch_bounds__(256) void k_initall(
    const int* __restrict__ ei, int E, int P, int* __restrict__ bcnt, int chunk,
    const float* __restrict__ W1, ushort* __restrict__ Wfr,
    const float* __restrict__ W2, const float* __restrict__ Wfv,
    const float* __restrict__ b2, const float* __restrict__ bfv,
    float* __restrict__ Wc) {
  int b = blockIdx.x;
  if (b < 128) {
    int g = b * 256 + threadIdx.x;
    int ii   = g & 7;
    int lane = (g >> 3) & 63;
    int t    = (g >> 9) & 7;
    int ks   = g >> 12;
    int k = ks * 32 + ((lane >> 4) << 3) + ii;
    int c = t * 16 + (lane & 15);
    Wfr[g] = f2bf(W1[(size_t)k * NH + c]);
  } else if (b == 128) {
    __shared__ float wl[NH];
    if (threadIdx.x < NH) wl[threadIdx.x] = Wfv[threadIdx.x];
    __syncthreads();
    if (threadIdx.x < NH) {
      int i = threadIdx.x;
      const float4* w4 = reinterpret_cast<const float4*>(&W2[(size_t)i * NH]);
      float s = 0.f;
#pragma unroll 8
      for (int k = 0; k < NH / 4; ++k) {
        float4 v = w4[k];
        s += v.x * wl[4 * k] + v.y * wl[4 * k + 1] + v.z * wl[4 * k + 2] + v.w * wl[4 * k + 3];
      }
      Wc[i] = s;
      if (i == 0) {
        float c = 0.f;
        for (int k = 0; k < NH; ++k) c += b2[k] * wl[k];
        Wc[NH] = c + bfv[0];
      }
    }
  } else {
    int cb = b - 129;
    __shared__ int hc[MAXP];
    for (int j = threadIdx.x; j < P; j += 256) hc[j] = 0;
    __syncthreads();
    int start = cb * chunk;
    int endE = min(start + chunk, E);
    if ((E & 3) == 0 && (start & 3) == 0) {
      int nvec = (endE - start) >> 2;
      const int4* dst4 = reinterpret_cast<const int4*>(&ei[E + start]);
      for (int q = threadIdx.x; q < nvec; q += 256) {
        int4 d = dst4[q];
        atomicAdd(&hc[d.x >> PSZ_SH], 1);
        atomicAdd(&hc[d.y >> PSZ_SH], 1);
        atomicAdd(&hc[d.z >> PSZ_SH], 1);
        atomicAdd(&hc[d.w >> PSZ_SH], 1);
      }
      for (int e = start + (nvec << 2) + (int)threadIdx.x; e < endE; e += 256)
        atomicAdd(&hc[ei[E + e] >> PSZ_SH], 1);
    } else {
      for (int e = start + (int)threadIdx.x; e < endE; e += 256)
        atomicAdd(&hc[ei[E + e] >> PSZ_SH], 1);
    }
    __syncthreads();
    for (int j = threadIdx.x; j < P; j += 256) bcnt[cb * P + j] = hc[j];
  }
}

// ---------------- scanA: per-bucket exclusive prefix over chunks; ptot ----------------
__global__ __launch_bounds__(NCB) void k_scanA(const int* __restrict__ bcnt,
                                               int* __restrict__ bloc,
                                               int* __restrict__ ptot, int P) {
  __shared__ int ws[NCB / 64];
  int p = blockIdx.x, tid = threadIdx.x, lane = tid & 63, wid = tid >> 6;
  int v = bcnt[tid * P + p];
  int pre = v;
#pragma unroll
  for (int m = 1; m < 64; m <<= 1) {
    int t = __shfl_up(pre, m, 64);
    if (lane >= m) pre += t;
  }
  if (lane == 63) ws[wid] = pre;
  __syncthreads();
  if (tid == 0) {
    int run = 0;
#pragma unroll
    for (int j = 0; j < NCB / 64; ++j) { int t = ws[j]; ws[j] = run; run += t; }
    ptot[p] = run;
  }
  __syncthreads();
  bloc[tid * P + p] = ws[wid] + pre - v;
}

// ---------------- scanB: exclusive scan of ptot -> pbase ----------------
__global__ __launch_bounds__(1024) void k_scanB(const int* __restrict__ ptot,
                                                int* __restrict__ pbase, int P, int E) {
  __shared__ int ws[16];
  int tid = threadIdx.x, lane = tid & 63, wid = tid >> 6;
  int v = (tid < P) ? ptot[tid] : 0;
  int pre = v;
#pragma unroll
  for (int m = 1; m < 64; m <<= 1) {
    int t = __shfl_up(pre, m, 64);
    if (lane >= m) pre += t;
  }
  if (lane == 63) ws[wid] = pre;
  __syncthreads();
  if (tid == 0) {
    int run = 0;
#pragma unroll
    for (int j = 0; j < 16; ++j) { int t = ws[j]; ws[j] = run; run += t; }
  }
  __syncthreads();
  if (tid < P) pbase[tid] = ws[wid] + pre - v;
  if (tid == 0) pbase[P] = E;
}

// ---------------- scatter: edges -> bucket-contiguous packed sub (LDS cursors) ----------------
__global__ __launch_bounds__(256) void k_scatter(const int* __restrict__ ei, int E,
                                                 const int* __restrict__ pbase,
                                                 const int* __restrict__ bloc,
                                                 uint* __restrict__ sub, int chunk, int P) {
  __shared__ int cur[MAXP];
  int b = blockIdx.x;
  for (int j = threadIdx.x; j < P; j += 256) cur[j] = pbase[j] + bloc[b * P + j];
  __syncthreads();
  int start = b * chunk;
  int endE = min(start + chunk, E);
  if ((E & 3) == 0 && (start & 3) == 0) {
    int nvec = (endE - start) >> 2;
    const int4* src4 = reinterpret_cast<const int4*>(&ei[start]);
    const int4* dst4 = reinterpret_cast<const int4*>(&ei[E + start]);
    for (int q = threadIdx.x; q < nvec; q += 256) {
      int4 s = src4[q];
      int4 d = dst4[q];
      int p0 = atomicAdd(&cur[d.x >> PSZ_SH], 1);
      sub[p0] = (uint)s.x | ((uint)(d.x & ((1 << PSZ_SH) - 1)) << 20);
      int p1 = atomicAdd(&cur[d.y >> PSZ_SH], 1);
      sub[p1] = (uint)s.y | ((uint)(d.y & ((1 << PSZ_SH) - 1)) << 20);
      int p2 = atomicAdd(&cur[d.z >> PSZ_SH], 1);
      sub[p2] = (uint)s.z | ((uint)(d.z & ((1 << PSZ_SH) - 1)) << 20);
      int p3 = atomicAdd(&cur[d.w >> PSZ_SH], 1);
      sub[p3] = (uint)s.w | ((uint)(d.w & ((1 << PSZ_SH) - 1)) << 20);
    }
    for (int e = start + (nvec << 2) + (int)threadIdx.x; e < endE; e += 256) {
      int s = ei[e];
      int d = ei[E + e];
      int pos = atomicAdd(&cur[d >> PSZ_SH], 1);
      sub[pos] = (uint)s | ((uint)(d & ((1 << PSZ_SH) - 1)) << 20);
    }
  } else {
    for (int e = start + (int)threadIdx.x; e < endE; e += 256) {
      int s = ei[e];
      int d = ei[E + e];
      int pos = atomicAdd(&cur[d >> PSZ_SH], 1);
      sub[pos] = (uint)s | ((uint)(d & ((1 << PSZ_SH) - 1)) << 20);
    }
  }
}

// ---------------- bucket: per-bucket hist -> rowptr/deg/dinv + csr fill (LDS only) ----------------
__global__ __launch_bounds__(256) void k_bucket(const uint* __restrict__ sub,
                                                const int* __restrict__ pbase,
                                                int* __restrict__ rowptr, int* __restrict__ deg,
                                                float* __restrict__ dinv, int* __restrict__ csr,
                                                int N) {
  __shared__ int hist[1 << PSZ_SH];
  __shared__ int curL[1 << PSZ_SH];
  __shared__ int wsum[2];
  const int p = blockIdx.x, tid = threadIdx.x;
  const int base = pbase[p];
  const int cnt = pbase[p + 1] - base;
  const int node0 = p << PSZ_SH;
  if (tid < (1 << PSZ_SH)) hist[tid] = 0;
  __syncthreads();
  for (int e = tid; e < cnt; e += 256) atomicAdd(&hist[sub[base + e] >> 20], 1);
  __syncthreads();
  int d = 0, pre = 0;
  if (tid < (1 << PSZ_SH)) {
    d = hist[tid];
    pre = d;
#pragma unroll
    for (int m = 1; m < 64; m <<= 1) {
      int t = __shfl_up(pre, m, 64);
      if ((tid & 63) >= m) pre += t;
    }
    if ((tid & 63) == 63) wsum[tid >> 6] = pre;
  }
  __syncthreads();
  if (tid < (1 << PSZ_SH)) {
    int excl = base + ((tid >= 64) ? wsum[0] : 0) + pre - d;
    curL[tid] = excl;
    int node = node0 + tid;
    if (node < N) {
      rowptr[node] = excl;
      deg[node] = d;
      dinv[node] = rsqrtf((float)d + 1.0f);
    }
  }
  __syncthreads();
  for (int e = tid; e < cnt; e += 256) {
    uint v = sub[base + e];
    int pos = atomicAdd(&curL[v >> 20], 1);
    csr[pos] = (int)(v & 0xFFFFFu);
  }
}

// ---------------- GEMM1 v3 (MFMA, phase-split MLP): hs = dinv * (x @ W1), bf16, row-major ----------------
__global__ __launch_bounds__(256, 2) void k_gemm1(
    const float* __restrict__ x, const ushort* __restrict__ Wf,
    const float* __restrict__ dinv, ushort* __restrict__ hs, int N) {
  __shared__ ushort Ol[64][136];
  const int tid = threadIdx.x;
  const int w = tid >> 6, l = tid & 63;
  const int row0 = blockIdx.x * 64;
  const int arow = row0 + 16 * w + (l & 15);
  const int kg = l >> 4;
  const bool rv = arow < N;
  const float* xr = &x[(size_t)(rv ? arow : 0) * NF + kg * 8];

  float4 xf0[8], xf1[8];
#pragma unroll
  for (int ks = 0; ks < 8; ++ks) {
    xf0[ks] = *reinterpret_cast<const float4*>(&xr[ks * 32]);
    xf1[ks] = *reinterpret_cast<const float4*>(&xr[ks * 32 + 4]);
  }
  __builtin_amdgcn_sched_barrier(0);

  short8 afr[8];
#pragma unroll
  for (int ks = 0; ks < 8; ++ks) {
    float4 v0 = xf0[ks], v1 = xf1[ks];
    if (!rv) { v0 = make_float4(0.f, 0.f, 0.f, 0.f); v1 = v0; }
    afr[ks] = pack_bf8(v0, v1);
  }

  const short8* Wb = reinterpret_cast<const short8*>(Wf);
  float4v acc[8];
#pragma unroll
  for (int t = 0; t < 8; ++t) acc[t] = (float4v){0.f, 0.f, 0.f, 0.f};
  short8 bc[8], bn[8];
#pragma unroll
  for (int ks = 0; ks < 8; ++ks) bc[ks] = Wb[(ks * 8 + 0) * 64 + l];
#pragma unroll
  for (int tp = 0; tp < 4; ++tp) {
    const int t0 = 2 * tp, t1 = 2 * tp + 1;
#pragma unroll
    for (int ks = 0; ks < 8; ++ks) bn[ks] = Wb[(ks * 8 + t1) * 64 + l];
    __builtin_amdgcn_sched_barrier(0);
#pragma unroll
    for (int ks = 0; ks < 8; ++ks)
      acc[t0] = __builtin_amdgcn_mfma_f32_16x16x32_bf16(afr[ks], bc[ks], acc[t0], 0, 0, 0);
    if (tp < 3) {
#pragma unroll
      for (int ks = 0; ks < 8; ++ks) bc[ks] = Wb[(ks * 8 + t1 + 1) * 64 + l];
      __builtin_amdgcn_sched_barrier(0);
    }
#pragma unroll
    for (int ks = 0; ks < 8; ++ks)
      acc[t1] = __builtin_amdgcn_mfma_f32_16x16x32_bf16(afr[ks], bn[ks], acc[t1], 0, 0, 0);
  }

  float dj[4];
#pragma unroll
  for (int j = 0; j < 4; ++j) {
    int grow = row0 + 16 * w + (l >> 4) * 4 + j;
    dj[j] = (grow < N) ? dinv[grow] : 0.f;
  }
#pragma unroll
  for (int t = 0; t < 8; ++t)
#pragma unroll
    for (int j = 0; j < 4; ++j)
      Ol[16 * w + (l >> 4) * 4 + j][16 * t + (l & 15)] = f2bf(acc[t][j] * dj[j]);
  __syncthreads();
  {
    const int r = tid >> 2, grow = row0 + r;
    if (grow < N) {
      uint* dsts = (uint*)hs;
#pragma unroll
      for (int q = 0; q < 4; ++q) {
        uint4 v = *reinterpret_cast<const uint4*>(&Ol[r][(tid & 3) * 32 + q * 8]);
        *reinterpret_cast<uint4*>(&dsts[(size_t)grow * 64 + (tid & 3) * 16 + q * 4]) = v;
      }
    }
  }
}

// ---------------- fused layer1 gather + relu + dot(Wc): wave/node, quarter-wave edges ----------------
static __device__ __forceinline__ void accg(float2* a, uint4 u) {
  a[0].x += __uint_as_float(u.x << 16); a[0].y += __uint_as_float(u.x);
  a[1].x += __uint_as_float(u.y << 16); a[1].y += __uint_as_float(u.y);
  a[2].x += __uint_as_float(u.z << 16); a[2].y += __uint_as_float(u.z);
  a[3].x += __uint_as_float(u.w << 16); a[3].y += __uint_as_float(u.w);
}

__global__ __launch_bounds__(256) void k_agg1_z(
    const uint4* __restrict__ hs4, const int* __restrict__ rowptr,
    const int* __restrict__ deg, const int* __restrict__ csr,
    const float* __restrict__ dinv, const float* __restrict__ b1,
    const float* __restrict__ Wc, float* __restrict__ zs,
    float* __restrict__ out, int N) {
  int g = blockIdx.x * blockDim.x + threadIdx.x;
  int i = g >> 6;
  if (i >= N) return;
  int lane = threadIdx.x & 63;
  int q = lane >> 4;        // quarter 0..3 -> edge slot
  int sub = lane & 15;      // 16 lanes x uint4 = 128 features

  float2 a2[4];
  {  // self-loop: quarter 0 only (exact unpack)
    uint4 u = hs4[(size_t)i * 16 + sub];
    if (q) { u.x = 0u; u.y = 0u; u.z = 0u; u.w = 0u; }
    a2[0] = make_float2(bflo(u.x), bfhi(u.x));
    a2[1] = make_float2(bflo(u.y), bfhi(u.y));
    a2[2] = make_float2(bflo(u.z), bfhi(u.z));
    a2[3] = make_float2(bflo(u.w), bfhi(u.w));
  }

  int kk = rowptr[i];
  const int end = kk + deg[i];
  for (; kk + 15 < end; kk += 16) {   // 16 edges/iter, 4 per quarter (4 loads in flight)
    int c0 = csr[kk + q];
    int c1 = csr[kk + 4 + q];
    int c2 = csr[kk + 8 + q];
    int c3 = csr[kk + 12 + q];
    uint4 u0 = hs4[(size_t)c0 * 16 + sub];
    uint4 u1 = hs4[(size_t)c1 * 16 + sub];
    uint4 u2 = hs4[(size_t)c2 * 16 + sub];
    uint4 u3 = hs4[(size_t)c3 * 16 + sub];
    accg(a2, u0); accg(a2, u1); accg(a2, u2); accg(a2, u3);
  }
  for (; kk + 3 < end; kk += 4) {     // 4 edges/iter
    int c = csr[kk + q];
    uint4 u = hs4[(size_t)c * 16 + sub];
    accg(a2, u);
  }
  int r = end - kk;                   // 0..3 leftover
  if (r > 0) {
    int c = csr[kk + (q < r ? q : r - 1)];
    uint4 u = hs4[(size_t)c * 16 + sub];
    if (q >= r) { u.x = 0u; u.y = 0u; u.z = 0u; u.w = 0u; }
    accg(a2, u);
  }

  float a[8] = {a2[0].x, a2[0].y, a2[1].x, a2[1].y, a2[2].x, a2[2].y, a2[3].x, a2[3].y};
#pragma unroll
  for (int j = 0; j < 8; ++j) {       // combine quarters
    a[j] += __shfl_xor(a[j], 16, 64);
    a[j] += __shfl_xor(a[j], 32, 64);
  }

  float d = dinv[i];
  float4 ba = reinterpret_cast<const float4*>(b1)[2 * sub];
  float4 bb = reinterpret_cast<const float4*>(b1)[2 * sub + 1];
  float4 wa = reinterpret_cast<const float4*>(Wc)[2 * sub];
  float4 wb = reinterpret_cast<const float4*>(Wc)[2 * sub + 1];
  float s = fmaxf(fmaf(d, a[0], ba.x), 0.f) * wa.x
          + fmaxf(fmaf(d, a[1], ba.y), 0.f) * wa.y
          + fmaxf(fmaf(d, a[2], ba.z), 0.f) * wa.z
          + fmaxf(fmaf(d, a[3], ba.w), 0.f) * wa.w
          + fmaxf(fmaf(d, a[4], bb.x), 0.f) * wb.x
          + fmaxf(fmaf(d, a[5], bb.y), 0.f) * wb.y
          + fmaxf(fmaf(d, a[6], bb.z), 0.f) * wb.z
          + fmaxf(fmaf(d, a[7], bb.w), 0.f) * wb.w;
#pragma unroll
  for (int m = 8; m >= 1; m >>= 1) s += __shfl_xor(s, m, 64);
  if (lane == 0) {
    float zsv = d * s;
    zs[i] = zsv;
    out[i] = d * zsv + Wc[NH];
  }
}

// ---------------- layer2 gather: out[i] += dinv[i] * sum zs[src] ----------------
__global__ void k_out2(const int* __restrict__ rowptr, const int* __restrict__ deg,
                       const int* __restrict__ csr, const float* __restrict__ zs,
                       const float* __restrict__ dinv, float* __restrict__ out, int N) {
  int i = blockIdx.x * blockDim.x + threadIdx.x;
  if (i >= N) return;
  int k = rowptr[i], end = k + deg[i];
  float s = 0.f;
  for (; k + 3 < end; k += 4) {
    float t0 = zs[csr[k]], t1 = zs[csr[k + 1]], t2 = zs[csr[k + 2]], t3 = zs[csr[k + 3]];
    s += (t0 + t1) + (t2 + t3);
  }
  for (; k < end; ++k) s += zs[csr[k]];
  out[i] += dinv[i] * s;
}

extern "C" void kernel_launch(void* const* d_in, const int* in_sizes, int n_in,
                              void* d_out, int out_size, void* d_ws, size_t ws_size,
                              hipStream_t stream) {
  const float* x  = (const float*)d_in[0];
  const int*   ei = (const int*)d_in[1];
  const float* W1 = (const float*)d_in[2];
  const float* b1 = (const float*)d_in[3];
  const float* W2 = (const float*)d_in[4];
  const float* b2 = (const float*)d_in[5];
  const float* Wf = (const float*)d_in[6];
  const float* bf = (const float*)d_in[7];
  const int N = in_sizes[0] / NF;
  const int E = in_sizes[1] / 2;
  const int P = (N + (1 << PSZ_SH) - 1) >> PSZ_SH;   // 782 buckets
  const int chunk = (((E + NCB - 1) / NCB) + 3) & ~3;  // multiple of 4 for int4 path

  char* ws = (char*)d_ws;
  size_t off = 0;
  auto alloc = [&](size_t bytes) {
    void* p = ws + off;
    off = (off + bytes + 255) & ~(size_t)255;
    return p;
  };
  ushort* hs     = (ushort*)alloc((size_t)N * NH * 2);    // 25.6 MB, row-major
  ushort* Wfrag  = (ushort*)alloc((size_t)NF * NH * 2);   // 64 KB
  int*    csr    = (int*)alloc((size_t)E * 4);            // 6.4 MB
  uint*   sub    = (uint*)alloc((size_t)E * 4);           // 6.4 MB
  int*    deg    = (int*)alloc((size_t)N * 4);
  int*    rowptr = (int*)alloc((size_t)N * 4);
  float*  dinv   = (float*)alloc((size_t)N * 4);
  float*  zs     = (float*)alloc((size_t)N * 4);
  float*  Wc     = (float*)alloc(132 * 4);
  int*    bcnt   = (int*)alloc((size_t)NCB * P * 4);      // 1.6 MB
  int*    bloc   = (int*)alloc((size_t)NCB * P * 4);      // 1.6 MB
  int*    ptot   = (int*)alloc((size_t)P * 4);
  int*    pbase  = (int*)alloc((size_t)(P + 1) * 4);
  float*  out    = (float*)d_out;

  const int b = 256;
  k_initall<<<129 + NCB, b, 0, stream>>>(ei, E, P, bcnt, chunk,
                                         W1, Wfrag, W2, Wf, b2, bf, Wc);
  k_scanA  <<<P, NCB, 0, stream>>>(bcnt, bloc, ptot, P);
  k_scanB  <<<1, 1024, 0, stream>>>(ptot, pbase, P, E);
  k_scatter<<<NCB, b, 0, stream>>>(ei, E, pbase, bloc, sub, chunk, P);
  k_bucket <<<P, b, 0, stream>>>(sub, pbase, rowptr, deg, dinv, csr, N);
  k_gemm1  <<<(N + 63) / 64, 256, 0, stream>>>(x, Wfrag, dinv, hs, N);
  k_agg1_z <<<(int)(((size_t)N * 64 + b - 1) / b), b, 0, stream>>>(
      (const uint4*)hs, rowptr, deg, csr, dinv, b1, Wc, zs, out, N);
  k_out2   <<<(N + b - 1) / b, b, 0, stream>>>(rowptr, deg, csr, zs, dinv, out, N);
}

// Round 13
// 155.985 us; speedup vs baseline: 1.7537x; 1.0090x over previous
//
#include <hip/hip_runtime.h>
#include <hip/hip_bf16.h>

#define NF 256
#define NH 128
#define PSZ_SH 7            // 128 nodes per bucket
#define MAXP 1024           // max buckets (N <= 131072)
#define NCB 512             // chunk blocks for count/scatter

typedef __attribute__((ext_vector_type(8))) short short8;
typedef __attribute__((ext_vector_type(4))) float float4v;

static __device__ __forceinline__ ushort f2bf(float f) {
  unsigned u = __float_as_uint(f);
  u = (u + 0x7fffu + ((u >> 16) & 1u)) >> 16;   // round-to-nearest-even
  return (ushort)u;
}
static __device__ __forceinline__ float bflo(unsigned u) { return __uint_as_float(u << 16); }
static __device__ __forceinline__ float bfhi(unsigned u) { return __uint_as_float(u & 0xffff0000u); }

static __device__ __forceinline__ short8 pack_bf8(float4 v0, float4 v1) {
  short8 r;
  r[0] = (short)f2bf(v0.x); r[1] = (short)f2bf(v0.y);
  r[2] = (short)f2bf(v0.z); r[3] = (short)f2bf(v0.w);
  r[4] = (short)f2bf(v1.x); r[5] = (short)f2bf(v1.y);
  r[6] = (short)f2bf(v1.z); r[7] = (short)f2bf(v1.w);
  return r;
}

// ------- initall: W1 frags [0,128) | Wc [128] | per-chunk bucket histograms [129, 129+NCB) -------
__global__ __launch_bounds__(256) void k_initall(
    const int* __restrict__ ei, int E, int P, int* __restrict__ bcnt, int chunk,
    const float* __restrict__ W1, ushort* __restrict__ Wfr,
    const float* __restrict__ W2, const float* __restrict__ Wfv,
    const float* __restrict__ b2, const float* __restrict__ bfv,
    float* __restrict__ Wc) {
  int b = blockIdx.x;
  if (b < 128) {
    int g = b * 256 + threadIdx.x;
    int ii   = g & 7;
    int lane = (g >> 3) & 63;
    int t    = (g >> 9) & 7;
    int ks   = g >> 12;
    int k = ks * 32 + ((lane >> 4) << 3) + ii;
    int c = t * 16 + (lane & 15);
    Wfr[g] = f2bf(W1[(size_t)k * NH + c]);
  } else if (b == 128) {
    __shared__ float wl[NH];
    if (threadIdx.x < NH) wl[threadIdx.x] = Wfv[threadIdx.x];
    __syncthreads();
    if (threadIdx.x < NH) {
      int i = threadIdx.x;
      const float4* w4 = reinterpret_cast<const float4*>(&W2[(size_t)i * NH]);
      float s = 0.f;
#pragma unroll 8
      for (int k = 0; k < NH / 4; ++k) {
        float4 v = w4[k];
        s += v.x * wl[4 * k] + v.y * wl[4 * k + 1] + v.z * wl[4 * k + 2] + v.w * wl[4 * k + 3];
      }
      Wc[i] = s;
      if (i == 0) {
        float c = 0.f;
        for (int k = 0; k < NH; ++k) c += b2[k] * wl[k];
        Wc[NH] = c + bfv[0];
      }
    }
  } else {
    int cb = b - 129;
    __shared__ int hc[MAXP];
    for (int j = threadIdx.x; j < P; j += 256) hc[j] = 0;
    __syncthreads();
    int start = cb * chunk;
    int endE = min(start + chunk, E);
    if ((E & 3) == 0 && (start & 3) == 0) {
      int nvec = (endE - start) >> 2;
      const int4* dst4 = reinterpret_cast<const int4*>(&ei[E + start]);
      for (int q = threadIdx.x; q < nvec; q += 256) {
        int4 d = dst4[q];
        atomicAdd(&hc[d.x >> PSZ_SH], 1);
        atomicAdd(&hc[d.y >> PSZ_SH], 1);
        atomicAdd(&hc[d.z >> PSZ_SH], 1);
        atomicAdd(&hc[d.w >> PSZ_SH], 1);
      }
      for (int e = start + (nvec << 2) + (int)threadIdx.x; e < endE; e += 256)
        atomicAdd(&hc[ei[E + e] >> PSZ_SH], 1);
    } else {
      for (int e = start + (int)threadIdx.x; e < endE; e += 256)
        atomicAdd(&hc[ei[E + e] >> PSZ_SH], 1);
    }
    __syncthreads();
    for (int j = threadIdx.x; j < P; j += 256) bcnt[cb * P + j] = hc[j];
  }
}

// ---------------- scanA: per-bucket exclusive prefix over chunks; ptot ----------------
__global__ __launch_bounds__(NCB) void k_scanA(const int* __restrict__ bcnt,
                                               int* __restrict__ bloc,
                                               int* __restrict__ ptot, int P) {
  __shared__ int ws[NCB / 64];
  int p = blockIdx.x, tid = threadIdx.x, lane = tid & 63, wid = tid >> 6;
  int v = bcnt[tid * P + p];
  int pre = v;
#pragma unroll
  for (int m = 1; m < 64; m <<= 1) {
    int t = __shfl_up(pre, m, 64);
    if (lane >= m) pre += t;
  }
  if (lane == 63) ws[wid] = pre;
  __syncthreads();
  if (tid == 0) {
    int run = 0;
#pragma unroll
    for (int j = 0; j < NCB / 64; ++j) { int t = ws[j]; ws[j] = run; run += t; }
    ptot[p] = run;
  }
  __syncthreads();
  bloc[tid * P + p] = ws[wid] + pre - v;
}

// ---------------- scanB: exclusive scan of ptot -> pbase ----------------
__global__ __launch_bounds__(1024) void k_scanB(const int* __restrict__ ptot,
                                                int* __restrict__ pbase, int P, int E) {
  __shared__ int ws[16];
  int tid = threadIdx.x, lane = tid & 63, wid = tid >> 6;
  int v = (tid < P) ? ptot[tid] : 0;
  int pre = v;
#pragma unroll
  for (int m = 1; m < 64; m <<= 1) {
    int t = __shfl_up(pre, m, 64);
    if (lane >= m) pre += t;
  }
  if (lane == 63) ws[wid] = pre;
  __syncthreads();
  if (tid == 0) {
    int run = 0;
#pragma unroll
    for (int j = 0; j < 16; ++j) { int t = ws[j]; ws[j] = run; run += t; }
  }
  __syncthreads();
  if (tid < P) pbase[tid] = ws[wid] + pre - v;
  if (tid == 0) pbase[P] = E;
}

// ---------------- scatter: edges -> bucket-contiguous packed sub (LDS cursors) ----------------
__global__ __launch_bounds__(256) void k_scatter(const int* __restrict__ ei, int E,
                                                 const int* __restrict__ pbase,
                                                 const int* __restrict__ bloc,
                                                 uint* __restrict__ sub, int chunk, int P) {
  __shared__ int cur[MAXP];
  int b = blockIdx.x;
  for (int j = threadIdx.x; j < P; j += 256) cur[j] = pbase[j] + bloc[b * P + j];
  __syncthreads();
  int start = b * chunk;
  int endE = min(start + chunk, E);
  if ((E & 3) == 0 && (start & 3) == 0) {
    int nvec = (endE - start) >> 2;
    const int4* src4 = reinterpret_cast<const int4*>(&ei[start]);
    const int4* dst4 = reinterpret_cast<const int4*>(&ei[E + start]);
    for (int q = threadIdx.x; q < nvec; q += 256) {
      int4 s = src4[q];
      int4 d = dst4[q];
      int p0 = atomicAdd(&cur[d.x >> PSZ_SH], 1);
      sub[p0] = (uint)s.x | ((uint)(d.x & ((1 << PSZ_SH) - 1)) << 20);
      int p1 = atomicAdd(&cur[d.y >> PSZ_SH], 1);
      sub[p1] = (uint)s.y | ((uint)(d.y & ((1 << PSZ_SH) - 1)) << 20);
      int p2 = atomicAdd(&cur[d.z >> PSZ_SH], 1);
      sub[p2] = (uint)s.z | ((uint)(d.z & ((1 << PSZ_SH) - 1)) << 20);
      int p3 = atomicAdd(&cur[d.w >> PSZ_SH], 1);
      sub[p3] = (uint)s.w | ((uint)(d.w & ((1 << PSZ_SH) - 1)) << 20);
    }
    for (int e = start + (nvec << 2) + (int)threadIdx.x; e < endE; e += 256) {
      int s = ei[e];
      int d = ei[E + e];
      int pos = atomicAdd(&cur[d >> PSZ_SH], 1);
      sub[pos] = (uint)s | ((uint)(d & ((1 << PSZ_SH) - 1)) << 20);
    }
  } else {
    for (int e = start + (int)threadIdx.x; e < endE; e += 256) {
      int s = ei[e];
      int d = ei[E + e];
      int pos = atomicAdd(&cur[d >> PSZ_SH], 1);
      sub[pos] = (uint)s | ((uint)(d & ((1 << PSZ_SH) - 1)) << 20);
    }
  }
}

// ---------------- bucket: per-bucket hist -> rowptr/deg/dinv + csr fill (LDS only), 512 thr ----------------
__global__ __launch_bounds__(512) void k_bucket(const uint* __restrict__ sub,
                                                const int* __restrict__ pbase,
                                                int* __restrict__ rowptr, int* __restrict__ deg,
                                                float* __restrict__ dinv, int* __restrict__ csr,
                                                int N) {
  __shared__ int hist[1 << PSZ_SH];
  __shared__ int curL[1 << PSZ_SH];
  __shared__ int wsum[2];
  const int p = blockIdx.x, tid = threadIdx.x;
  const int base = pbase[p];
  const int cnt = pbase[p + 1] - base;
  const int node0 = p << PSZ_SH;
  if (tid < (1 << PSZ_SH)) hist[tid] = 0;
  __syncthreads();
  for (int e = tid; e < cnt; e += 512) atomicAdd(&hist[sub[base + e] >> 20], 1);
  __syncthreads();
  int d = 0, pre = 0;
  if (tid < (1 << PSZ_SH)) {
    d = hist[tid];
    pre = d;
#pragma unroll
    for (int m = 1; m < 64; m <<= 1) {
      int t = __shfl_up(pre, m, 64);
      if ((tid & 63) >= m) pre += t;
    }
    if ((tid & 63) == 63) wsum[tid >> 6] = pre;
  }
  __syncthreads();
  if (tid < (1 << PSZ_SH)) {
    int excl = base + ((tid >= 64) ? wsum[0] : 0) + pre - d;
    curL[tid] = excl;
    int node = node0 + tid;
    if (node < N) {
      rowptr[node] = excl;
      deg[node] = d;
      dinv[node] = rsqrtf((float)d + 1.0f);
    }
  }
  __syncthreads();
  for (int e = tid; e < cnt; e += 512) {
    uint v = sub[base + e];
    int pos = atomicAdd(&curL[v >> 20], 1);
    csr[pos] = (int)(v & 0xFFFFFu);
  }
}

// ---------------- GEMM1 v4 (MFMA, K-split staging, 3 waves/SIMD): hs = dinv*(x@W1) ----------------
__global__ __launch_bounds__(256, 3) void k_gemm1(
    const float* __restrict__ x, const ushort* __restrict__ Wf,
    const float* __restrict__ dinv, ushort* __restrict__ hs, int N) {
  __shared__ ushort Ol[64][136];
  const int tid = threadIdx.x;
  const int w = tid >> 6, l = tid & 63;
  const int row0 = blockIdx.x * 64;
  const int arow = row0 + 16 * w + (l & 15);
  const int kg = l >> 4;
  const bool rv = arow < N;
  const float* xr = &x[(size_t)(rv ? arow : 0) * NF + kg * 8];
  const short8* Wb = reinterpret_cast<const short8*>(Wf);

  float4v acc[8];
#pragma unroll
  for (int t = 0; t < 8; ++t) acc[t] = (float4v){0.f, 0.f, 0.f, 0.f};

  // ---- stage half 0 (K cols 0..127): 8 float4 ----
  float4 xf[8];
#pragma unroll
  for (int ks = 0; ks < 4; ++ks) {
    xf[2 * ks]     = *reinterpret_cast<const float4*>(&xr[ks * 32]);
    xf[2 * ks + 1] = *reinterpret_cast<const float4*>(&xr[ks * 32 + 4]);
  }
  __builtin_amdgcn_sched_barrier(0);
  short8 afr0[4];
#pragma unroll
  for (int ks = 0; ks < 4; ++ks) {
    float4 v0 = xf[2 * ks], v1 = xf[2 * ks + 1];
    if (!rv) { v0 = make_float4(0.f, 0.f, 0.f, 0.f); v1 = v0; }
    afr0[ks] = pack_bf8(v0, v1);
  }
  // ---- issue half-1 loads now; they fly during half-0 MFMAs ----
#pragma unroll
  for (int ks = 0; ks < 4; ++ks) {
    xf[2 * ks]     = *reinterpret_cast<const float4*>(&xr[(ks + 4) * 32]);
    xf[2 * ks + 1] = *reinterpret_cast<const float4*>(&xr[(ks + 4) * 32 + 4]);
  }
  __builtin_amdgcn_sched_barrier(0);

  // ---- half 0 MFMAs with B double-buffer ----
  {
    short8 bc[4], bn[4];
#pragma unroll
    for (int ks = 0; ks < 4; ++ks) bc[ks] = Wb[(ks * 8 + 0) * 64 + l];
#pragma unroll
    for (int t = 0; t < 8; ++t) {
      if (t < 7) {
#pragma unroll
        for (int ks = 0; ks < 4; ++ks) bn[ks] = Wb[(ks * 8 + t + 1) * 64 + l];
      }
      __builtin_amdgcn_sched_barrier(0);
#pragma unroll
      for (int ks = 0; ks < 4; ++ks)
        acc[t] = __builtin_amdgcn_mfma_f32_16x16x32_bf16(afr0[ks], bc[ks], acc[t], 0, 0, 0);
#pragma unroll
      for (int ks = 0; ks < 4; ++ks) bc[ks] = bn[ks];
    }
  }

  // ---- pack half 1, then its MFMAs ----
  short8 afr1[4];
#pragma unroll
  for (int ks = 0; ks < 4; ++ks) {
    float4 v0 = xf[2 * ks], v1 = xf[2 * ks + 1];
    if (!rv) { v0 = make_float4(0.f, 0.f, 0.f, 0.f); v1 = v0; }
    afr1[ks] = pack_bf8(v0, v1);
  }
  {
    short8 bc[4], bn[4];
#pragma unroll
    for (int ks = 0; ks < 4; ++ks) bc[ks] = Wb[((ks + 4) * 8 + 0) * 64 + l];
#pragma unroll
    for (int t = 0; t < 8; ++t) {
      if (t < 7) {
#pragma unroll
        for (int ks = 0; ks < 4; ++ks) bn[ks] = Wb[((ks + 4) * 8 + t + 1) * 64 + l];
      }
      __builtin_amdgcn_sched_barrier(0);
#pragma unroll
      for (int ks = 0; ks < 4; ++ks)
        acc[t] = __builtin_amdgcn_mfma_f32_16x16x32_bf16(afr1[ks], bc[ks], acc[t], 0, 0, 0);
#pragma unroll
      for (int ks = 0; ks < 4; ++ks) bc[ks] = bn[ks];
    }
  }

  // epilogue: scale by dinv, bf16, transpose via LDS, coalesced store
  float dj[4];
#pragma unroll
  for (int j = 0; j < 4; ++j) {
    int grow = row0 + 16 * w + (l >> 4) * 4 + j;
    dj[j] = (grow < N) ? dinv[grow] : 0.f;
  }
#pragma unroll
  for (int t = 0; t < 8; ++t)
#pragma unroll
    for (int j = 0; j < 4; ++j)
      Ol[16 * w + (l >> 4) * 4 + j][16 * t + (l & 15)] = f2bf(acc[t][j] * dj[j]);
  __syncthreads();
  {
    const int r = tid >> 2, grow = row0 + r;
    if (grow < N) {
      uint* dsts = (uint*)hs;
#pragma unroll
      for (int q = 0; q < 4; ++q) {
        uint4 v = *reinterpret_cast<const uint4*>(&Ol[r][(tid & 3) * 32 + q * 8]);
        *reinterpret_cast<uint4*>(&dsts[(size_t)grow * 64 + (tid & 3) * 16 + q * 4]) = v;
      }
    }
  }
}

// ---------------- fused layer1 gather + relu + dot(Wc): wave/node, quarter-wave edges ----------------
static __device__ __forceinline__ void accg(float2* a, uint4 u) {
  a[0].x += __uint_as_float(u.x << 16); a[0].y += __uint_as_float(u.x);
  a[1].x += __uint_as_float(u.y << 16); a[1].y += __uint_as_float(u.y);
  a[2].x += __uint_as_float(u.z << 16); a[2].y += __uint_as_float(u.z);
  a[3].x += __uint_as_float(u.w << 16); a[3].y += __uint_as_float(u.w);
}

__global__ __launch_bounds__(256) void k_agg1_z(
    const uint4* __restrict__ hs4, const int* __restrict__ rowptr,
    const int* __restrict__ deg, const int* __restrict__ csr,
    const float* __restrict__ dinv, const float* __restrict__ b1,
    const float* __restrict__ Wc, float* __restrict__ zs,
    float* __restrict__ out, int N) {
  int g = blockIdx.x * blockDim.x + threadIdx.x;
  int i = g >> 6;
  if (i >= N) return;
  int lane = threadIdx.x & 63;
  int q = lane >> 4;        // quarter 0..3 -> edge slot
  int sub = lane & 15;      // 16 lanes x uint4 = 128 features

  float2 a2[4];
  {  // self-loop: quarter 0 only (exact unpack)
    uint4 u = hs4[(size_t)i * 16 + sub];
    if (q) { u.x = 0u; u.y = 0u; u.z = 0u; u.w = 0u; }
    a2[0] = make_float2(bflo(u.x), bfhi(u.x));
    a2[1] = make_float2(bflo(u.y), bfhi(u.y));
    a2[2] = make_float2(bflo(u.z), bfhi(u.z));
    a2[3] = make_float2(bflo(u.w), bfhi(u.w));
  }

  int kk = rowptr[i];
  const int end = kk + deg[i];
  for (; kk + 15 < end; kk += 16) {   // 16 edges/iter, 4 per quarter (4 loads in flight)
    int c0 = csr[kk + q];
    int c1 = csr[kk + 4 + q];
    int c2 = csr[kk + 8 + q];
    int c3 = csr[kk + 12 + q];
    uint4 u0 = hs4[(size_t)c0 * 16 + sub];
    uint4 u1 = hs4[(size_t)c1 * 16 + sub];
    uint4 u2 = hs4[(size_t)c2 * 16 + sub];
    uint4 u3 = hs4[(size_t)c3 * 16 + sub];
    accg(a2, u0); accg(a2, u1); accg(a2, u2); accg(a2, u3);
  }
  for (; kk + 3 < end; kk += 4) {     // 4 edges/iter
    int c = csr[kk + q];
    uint4 u = hs4[(size_t)c * 16 + sub];
    accg(a2, u);
  }
  int r = end - kk;                   // 0..3 leftover
  if (r > 0) {
    int c = csr[kk + (q < r ? q : r - 1)];
    uint4 u = hs4[(size_t)c * 16 + sub];
    if (q >= r) { u.x = 0u; u.y = 0u; u.z = 0u; u.w = 0u; }
    accg(a2, u);
  }

  float a[8] = {a2[0].x, a2[0].y, a2[1].x, a2[1].y, a2[2].x, a2[2].y, a2[3].x, a2[3].y};
#pragma unroll
  for (int j = 0; j < 8; ++j) {       // combine quarters
    a[j] += __shfl_xor(a[j], 16, 64);
    a[j] += __shfl_xor(a[j], 32, 64);
  }

  float d = dinv[i];
  float4 ba = reinterpret_cast<const float4*>(b1)[2 * sub];
  float4 bb = reinterpret_cast<const float4*>(b1)[2 * sub + 1];
  float4 wa = reinterpret_cast<const float4*>(Wc)[2 * sub];
  float4 wb = reinterpret_cast<const float4*>(Wc)[2 * sub + 1];
  float s = fmaxf(fmaf(d, a[0], ba.x), 0.f) * wa.x
          + fmaxf(fmaf(d, a[1], ba.y), 0.f) * wa.y
          + fmaxf(fmaf(d, a[2], ba.z), 0.f) * wa.z
          + fmaxf(fmaf(d, a[3], ba.w), 0.f) * wa.w
          + fmaxf(fmaf(d, a[4], bb.x), 0.f) * wb.x
          + fmaxf(fmaf(d, a[5], bb.y), 0.f) * wb.y
          + fmaxf(fmaf(d, a[6], bb.z), 0.f) * wb.z
          + fmaxf(fmaf(d, a[7], bb.w), 0.f) * wb.w;
#pragma unroll
  for (int m = 8; m >= 1; m >>= 1) s += __shfl_xor(s, m, 64);
  if (lane == 0) {
    float zsv = d * s;
    zs[i] = zsv;
    out[i] = d * zsv + Wc[NH];
  }
}

// ---------------- layer2 gather: out[i] += dinv[i] * sum zs[src], 8-unrolled ----------------
__global__ void k_out2(const int* __restrict__ rowptr, const int* __restrict__ deg,
                       const int* __restrict__ csr, const float* __restrict__ zs,
                       const float* __restrict__ dinv, float* __restrict__ out, int N) {
  int i = blockIdx.x * blockDim.x + threadIdx.x;
  if (i >= N) return;
  int k = rowptr[i], end = k + deg[i];
  float s0 = 0.f, s1 = 0.f;
  for (; k + 7 < end; k += 8) {
    float t0 = zs[csr[k]],     t1 = zs[csr[k + 1]];
    float t2 = zs[csr[k + 2]], t3 = zs[csr[k + 3]];
    float t4 = zs[csr[k + 4]], t5 = zs[csr[k + 5]];
    float t6 = zs[csr[k + 6]], t7 = zs[csr[k + 7]];
    s0 += (t0 + t1) + (t2 + t3);
    s1 += (t4 + t5) + (t6 + t7);
  }
  for (; k < end; ++k) s0 += zs[csr[k]];
  out[i] += dinv[i] * (s0 + s1);
}

extern "C" void kernel_launch(void* const* d_in, const int* in_sizes, int n_in,
                              void* d_out, int out_size, void* d_ws, size_t ws_size,
                              hipStream_t stream) {
  const float* x  = (const float*)d_in[0];
  const int*   ei = (const int*)d_in[1];
  const float* W1 = (const float*)d_in[2];
  const float* b1 = (const float*)d_in[3];
  const float* W2 = (const float*)d_in[4];
  const float* b2 = (const float*)d_in[5];
  const float* Wf = (const float*)d_in[6];
  const float* bf = (const float*)d_in[7];
  const int N = in_sizes[0] / NF;
  const int E = in_sizes[1] / 2;
  const int P = (N + (1 << PSZ_SH) - 1) >> PSZ_SH;   // 782 buckets
  const int chunk = (((E + NCB - 1) / NCB) + 3) & ~3;  // multiple of 4 for int4 path

  char* ws = (char*)d_ws;
  size_t off = 0;
  auto alloc = [&](size_t bytes) {
    void* p = ws + off;
    off = (off + bytes + 255) & ~(size_t)255;
    return p;
  };
  ushort* hs     = (ushort*)alloc((size_t)N * NH * 2);    // 25.6 MB, row-major
  ushort* Wfrag  = (ushort*)alloc((size_t)NF * NH * 2);   // 64 KB
  int*    csr    = (int*)alloc((size_t)E * 4);            // 6.4 MB
  uint*   sub    = (uint*)alloc((size_t)E * 4);           // 6.4 MB
  int*    deg    = (int*)alloc((size_t)N * 4);
  int*    rowptr = (int*)alloc((size_t)N * 4);
  float*  dinv   = (float*)alloc((size_t)N * 4);
  float*  zs     = (float*)alloc((size_t)N * 4);
  float*  Wc     = (float*)alloc(132 * 4);
  int*    bcnt   = (int*)alloc((size_t)NCB * P * 4);      // 1.6 MB
  int*    bloc   = (int*)alloc((size_t)NCB * P * 4);      // 1.6 MB
  int*    ptot   = (int*)alloc((size_t)P * 4);
  int*    pbase  = (int*)alloc((size_t)(P + 1) * 4);
  float*  out    = (float*)d_out;

  const int b = 256;
  k_initall<<<129 + NCB, b, 0, stream>>>(ei, E, P, bcnt, chunk,
                                         W1, Wfrag, W2, Wf, b2, bf, Wc);
  k_scanA  <<<P, NCB, 0, stream>>>(bcnt, bloc, ptot, P);
  k_scanB  <<<1, 1024, 0, stream>>>(ptot, pbase, P, E);
  k_scatter<<<NCB, b, 0, stream>>>(ei, E, pbase, bloc, sub, chunk, P);
  k_bucket <<<P, 512, 0, stream>>>(sub, pbase, rowptr, deg, dinv, csr, N);
  k_gemm1  <<<(N + 63) / 64, 256, 0, stream>>>(x, Wfrag, dinv, hs, N);
  k_agg1_z <<<(int)(((size_t)N * 64 + b - 1) / b), b, 0, stream>>>(
      (const uint4*)hs, rowptr, deg, csr, dinv, b1, Wc, zs, out, N);
  k_out2   <<<(N + b - 1) / b, b, 0, stream>>>(rowptr, deg, csr, zs, dinv, out, N);
}